// Round 7
// baseline (122.995 us; speedup 1.0000x reference)
//
#include <hip/hip_runtime.h>

typedef short short8 __attribute__((ext_vector_type(8)));
typedef float f32x16 __attribute__((ext_vector_type(16)));

#define BN 4096
#define DD 128
#define MARGIN 0.3f
#define HP_INIT_BITS 0xBF800000u   /* -1.0f : "no positive seen" sentinel */
#define HN_INITF 1e30f

// round-to-nearest-even f32 -> bf16 bits (inputs finite; no NaN guard needed)
__device__ __forceinline__ unsigned short f2bf(float x) {
    unsigned u = __float_as_uint(x);
    return (unsigned short)((u + 0x7FFFu + ((u >> 16) & 1u)) >> 16);
}
__device__ __forceinline__ float bf2f(unsigned short b) {
    return __uint_as_float(((unsigned)b) << 16);
}
// 8 f32 -> packed hi(8 bf16) + lo(8 bf16 residual)
__device__ __forceinline__ void cvt8(float4 f0, float4 f1, int4& hi, int4& lo) {
    float x[8] = {f0.x, f0.y, f0.z, f0.w, f1.x, f1.y, f1.z, f1.w};
    unsigned hw[4], lw[4];
#pragma unroll
    for (int i = 0; i < 4; ++i) {
        unsigned short h0 = f2bf(x[2 * i]), h1 = f2bf(x[2 * i + 1]);
        hw[i] = (unsigned)h0 | ((unsigned)h1 << 16);
        lw[i] = (unsigned)f2bf(x[2 * i] - bf2f(h0)) |
                ((unsigned)f2bf(x[2 * i + 1] - bf2f(h1)) << 16);
    }
    hi = make_int4(hw[0], hw[1], hw[2], hw[3]);
    lo = make_int4(lw[0], lw[1], lw[2], lw[3]);
}

// ---------------- K1: sq-norms + init hp/hn (+ optional hi/lo split) ----------------
template<bool SPLIT>
__global__ __launch_bounds__(256) void k1_prep(
        const float* __restrict__ emb,
        unsigned* __restrict__ ehi, unsigned* __restrict__ elo,
        float* __restrict__ sqn, int* __restrict__ hp, int* __restrict__ hn) {
    const int r = blockIdx.x * 4 + (threadIdx.x >> 6);
    const int l = threadIdx.x & 63;
    const float2 v = *reinterpret_cast<const float2*>(emb + (size_t)r * DD + l * 2);

    if constexpr (SPLIT) {
        unsigned short h0 = f2bf(v.x), h1 = f2bf(v.y);
        unsigned short l0 = f2bf(v.x - bf2f(h0)), l1 = f2bf(v.y - bf2f(h1));
        ehi[r * 64 + l] = (unsigned)h0 | ((unsigned)h1 << 16);
        elo[r * 64 + l] = (unsigned)l0 | ((unsigned)l1 << 16);
    }
    float s = v.x * v.x + v.y * v.y;
#pragma unroll
    for (int m = 1; m < 64; m <<= 1) s += __shfl_xor(s, m);
    if (l == 0) {
        sqn[r] = s;
        hp[r] = (int)HP_INIT_BITS;
        hn[r] = __float_as_int(HN_INITF);
    }
}

// ---------------- K2: 3-pass bf16-split MFMA Gram + fused masked row max/min on d2 ----
// grid (32,32), block 256 = 4 waves; block tile 128x128; wave tile 64x64 (2x2 of 32x32)
// PRESPLIT: read precomputed ehi/elo.  else: read f32 emb, split in-register (48KB-ws-safe).
template<bool PRESPLIT>
__global__ __launch_bounds__(256) void k2_pairs(
        const unsigned short* __restrict__ ehi, const unsigned short* __restrict__ elo,
        const float* __restrict__ emb,
        const float* __restrict__ sqn, const int* __restrict__ labels,
        int* __restrict__ hp, int* __restrict__ hn) {
    // 4 tiles [128 rows][64 k] bf16 (16 KB each): Ah | Al | Bh | Bl.  XOR-swizzled rows.
    __shared__ __align__(16) char lds[65536];

    const int t    = threadIdx.x;
    const int srow = t >> 3;          // staging: row mod 32
    const int ss   = t & 7;           // staging: 16B-(bf16)/32B-(f32) slot = 8 elems
    const int w    = t >> 6;          // wave 0..3
    const int l    = t & 63;
    const int l31  = l & 31;
    const int kg   = l >> 5;          // k-group half
    const int Rw   = (w >> 1) * 64;   // wave row range in block
    const int Cw   = (w & 1) * 64;    // wave col range in block
    const int rowBase = blockIdx.y * 128;
    const int colBase = blockIdx.x * 128;

    f32x16 acc[2][2];
#pragma unroll
    for (int a = 0; a < 2; ++a)
#pragma unroll
        for (int b = 0; b < 2; ++b)
#pragma unroll
            for (int i = 0; i < 16; ++i) acc[a][b][i] = 0.0f;

    int4 stg[16];   // 256B/thread either way (presplit: 2 arrays x 16B; f32: 1 array x 32B)

    auto STAGE_LOAD = [&](int p) {   // T14 issue phase: global -> regs
        if constexpr (PRESPLIT) {
#pragma unroll
            for (int g = 0; g < 4; ++g)
#pragma unroll
                for (int q = 0; q < 4; ++q) {
                    const int row = q * 32 + srow;
                    const unsigned short* src = (g & 1) ? elo : ehi;
                    const int rb = (g < 2) ? rowBase : colBase;
                    stg[g * 4 + q] = *reinterpret_cast<const int4*>(
                        src + (size_t)(rb + row) * DD + p * 64 + ss * 8);
                }
        } else {
#pragma unroll
            for (int ga = 0; ga < 2; ++ga)
#pragma unroll
                for (int q = 0; q < 4; ++q)
#pragma unroll
                    for (int h = 0; h < 2; ++h) {
                        const int row = q * 32 + srow;
                        const int rb = ga ? colBase : rowBase;
                        stg[(ga * 4 + q) * 2 + h] = *reinterpret_cast<const int4*>(
                            emb + (size_t)(rb + row) * DD + p * 64 + ss * 8 + h * 4);
                    }
        }
    };
    auto STAGE_WRITE = [&]() {       // T14 write phase: regs -> swizzled LDS (+split if f32)
        if constexpr (PRESPLIT) {
#pragma unroll
            for (int g = 0; g < 4; ++g)
#pragma unroll
                for (int q = 0; q < 4; ++q) {
                    const int row = q * 32 + srow;
                    *reinterpret_cast<int4*>(lds + g * 16384 + row * 128 +
                                             ((ss ^ (row & 7)) << 4)) = stg[g * 4 + q];
                }
        } else {
#pragma unroll
            for (int ga = 0; ga < 2; ++ga)
#pragma unroll
                for (int q = 0; q < 4; ++q) {
                    const int row = q * 32 + srow;
                    int4 hi, lo;
                    cvt8(__builtin_bit_cast(float4, stg[(ga * 4 + q) * 2]),
                         __builtin_bit_cast(float4, stg[(ga * 4 + q) * 2 + 1]), hi, lo);
                    const int off = row * 128 + ((ss ^ (row & 7)) << 4);
                    *reinterpret_cast<int4*>(lds + (ga * 2) * 16384 + off)     = hi;
                    *reinterpret_cast<int4*>(lds + (ga * 2 + 1) * 16384 + off) = lo;
                }
        }
    };
    auto CHUNKS = [&]() {   // 4 chunks of K=16 over the staged 64-k phase; no barriers inside
#pragma unroll
        for (int c = 0; c < 4; ++c) {
            short8 ah[2], al[2], bh[2], bl[2];
#pragma unroll
            for (int a = 0; a < 2; ++a) {
                const int row = Rw + a * 32 + l31;
                const int off = row * 128 + (((c * 2 + kg) ^ (row & 7)) << 4);
                ah[a] = *reinterpret_cast<const short8*>(lds + off);
                al[a] = *reinterpret_cast<const short8*>(lds + 16384 + off);
            }
#pragma unroll
            for (int b = 0; b < 2; ++b) {
                const int row = Cw + b * 32 + l31;
                const int off = row * 128 + (((c * 2 + kg) ^ (row & 7)) << 4);
                bh[b] = *reinterpret_cast<const short8*>(lds + 32768 + off);
                bl[b] = *reinterpret_cast<const short8*>(lds + 49152 + off);
            }
#pragma unroll
            for (int a = 0; a < 2; ++a)
#pragma unroll
                for (int b = 0; b < 2; ++b) {
                    acc[a][b] = __builtin_amdgcn_mfma_f32_32x32x16_bf16(ah[a], bh[b], acc[a][b], 0, 0, 0);
                    acc[a][b] = __builtin_amdgcn_mfma_f32_32x32x16_bf16(ah[a], bl[b], acc[a][b], 0, 0, 0);
                    acc[a][b] = __builtin_amdgcn_mfma_f32_32x32x16_bf16(al[a], bh[b], acc[a][b], 0, 0, 0);
                }
        }
    };

    STAGE_LOAD(0);
    STAGE_WRITE();
    __syncthreads();        // phase-0 tiles visible
    STAGE_LOAD(1);          // issue phase-1 globals EARLY: latency hides under CHUNKS (T14)
    CHUNKS();               // k 0..63
    __syncthreads();        // everyone done READING phase-0 tiles
    STAGE_WRITE();
    __syncthreads();        // phase-1 tiles visible
    CHUNKS();               // k 64..127
    __syncthreads();        // tiles dead -> LDS becomes per-wave scratch

    // ---- epilogue: d2 + masks + per-row max/min, LDS-transpose reduce, atomics ----
    float sqJ[2]; int labJ[2], jg[2];
#pragma unroll
    for (int b = 0; b < 2; ++b) {
        jg[b]   = colBase + Cw + b * 32 + l31;
        sqJ[b]  = sqn[jg[b]];
        labJ[b] = labels[jg[b]];
    }
    char* scr = lds + w * 16384;   // per-wave [64 rows][32 cols] of {hp,hn} f32 pairs
#pragma unroll
    for (int a = 0; a < 2; ++a) {
#pragma unroll
        for (int rr = 0; rr < 16; ++rr) {
            const int crow = (rr & 3) + 8 * (rr >> 2) + 4 * kg;   // HW C/D row mapping (m74/m101)
            const int ig = rowBase + Rw + a * 32 + crow;
            const float sI = sqn[ig];
            const int   lI = labels[ig];
            float hpv = -1.0f, hnv = HN_INITF;
#pragma unroll
            for (int b = 0; b < 2; ++b) {
                const float v  = acc[a][b][rr];
                const float d2 = fmaf(-2.0f, v, sI + sqJ[b]);
                const bool same = (lI == labJ[b]);
                const float pc = (same && ig != jg[b]) ? fmaxf(d2, 0.0f) : -1.0f;
                const float nc = same ? HN_INITF : d2;
                hpv = fmaxf(hpv, pc);
                hnv = fminf(hnv, nc);
            }
            float2* slot = reinterpret_cast<float2*>(scr + ((a * 32 + crow) * 32 + l31) * 8);
            *slot = make_float2(hpv, hnv);
        }
    }
    // same-wave LDS ordering: compiler inserts lgkmcnt before dependent reads
    float hpr = -1.0f, hnr = HN_INITF;
#pragma unroll
    for (int c = 0; c < 32; ++c) {
        const int cc = (c + l31) & 31;   // rotated read -> conflict-free
        const float2 pv = *reinterpret_cast<const float2*>(scr + l * 256 + cc * 8);
        hpr = fmaxf(hpr, pv.x);
        hnr = fminf(hnr, pv.y);
    }
    const int ig = rowBase + Rw + l;
    atomicMax(hp + ig, __float_as_int(hpr));   // values >= 0 or -1.0 sentinel: int-monotone
    atomicMin(hn + ig, __float_as_int(hnr));   // positives int-monotone; all negatives clamp
                                               // identically in K3 -> order-reversal harmless
}

// ---------------- K3: per-row sqrt + loss + mean over valid ----------------
__global__ __launch_bounds__(1024) void k3_loss(
        const int* __restrict__ hp, const int* __restrict__ hn, float* __restrict__ out) {
    __shared__ float sS[16], sC[16];
    const int t = threadIdx.x;
    float sum = 0.f, cnt = 0.f;
#pragma unroll
    for (int q = 0; q < BN / 1024; ++q) {
        const int r = t + 1024 * q;
        const int pb = hp[r];
        const float n2 = __int_as_float(hn[r]);
        if (pb != (int)HP_INIT_BITS && n2 < 1e29f) {
            const float dp = sqrtf(fmaxf(__int_as_float(pb), 1e-12f));
            const float dn = sqrtf(fmaxf(n2, 1e-12f));
            sum += fmaxf(dp - dn + MARGIN, 0.f);
            cnt += 1.f;
        }
    }
#pragma unroll
    for (int off = 32; off > 0; off >>= 1) {
        sum += __shfl_down(sum, off);
        cnt += __shfl_down(cnt, off);
    }
    const int wv = t >> 6;
    if ((t & 63) == 0) { sS[wv] = sum; sC[wv] = cnt; }
    __syncthreads();
    if (t == 0) {
        float S = 0.f, C = 0.f;
#pragma unroll
        for (int q = 0; q < 16; ++q) { S += sS[q]; C += sC[q]; }
        out[0] = S / fmaxf(C, 1.f);
    }
}

extern "C" void kernel_launch(void* const* d_in, const int* in_sizes, int n_in,
                              void* d_out, int out_size, void* d_ws, size_t ws_size,
                              hipStream_t stream) {
    const float* emb    = (const float*)d_in[0];
    const int*   labels = (const int*)d_in[1];
    char* ws = (char*)d_ws;
    float* out = (float*)d_out;

    const size_t SPLIT_BYTES = (size_t)2u << 20;           // ehi+elo: 2 x 1 MB
    const bool presplit = ws_size >= SPLIT_BYTES + 3 * 16384;

    unsigned* ehi = (unsigned*)ws;
    unsigned* elo = (unsigned*)(ws + (1u << 20));
    char* base = presplit ? (ws + SPLIT_BYTES) : ws;       // never beyond 48KB if small ws
    float* sqn = (float*)base;
    int*   hp  = (int*)(base + 16384);
    int*   hn  = (int*)(base + 32768);

    dim3 g2(BN / 128, BN / 128);   // (32,32) = 1024 blocks, 2/CU at 64KB LDS
    if (presplit) {
        k1_prep<true><<<BN / 4, 256, 0, stream>>>(emb, ehi, elo, sqn, hp, hn);
        k2_pairs<true><<<g2, 256, 0, stream>>>((const unsigned short*)ehi,
                                               (const unsigned short*)elo,
                                               emb, sqn, labels, hp, hn);
    } else {
        k1_prep<false><<<BN / 4, 256, 0, stream>>>(emb, nullptr, nullptr, sqn, hp, hn);
        k2_pairs<false><<<g2, 256, 0, stream>>>(nullptr, nullptr,
                                                emb, sqn, labels, hp, hn);
    }
    k3_loss<<<1, 1024, 0, stream>>>(hp, hn, out);
}